// Round 3
// baseline (463.219 us; speedup 1.0000x reference)
//
#include <hip/hip_runtime.h>

// SpatialPool: fm [B=16, C=512, H=38, W=38] f32, replication pad 1,
// out[b, (h*W+w)*9*C + k*C + c] = fm[b, c, clamp(h+k/3-1), clamp(w+k%3-1)]
//
// R8c: same experiment as R8/R8b (gather + XCD-pinned input reuse + contiguous
// store streams) -- rounds 1 and 2 both died with "container failed twice"
// (infra; kernel never executed, source OOB-audited clean). Structurally
// simplified in case the previous shape deterministically tripped the stack:
//  - HALF-split: block = (b, h', half) -> 16*38*2 = 1216 blocks (4.75/CU,
//    1.053 imbalance). 2 template instantiations (was 4), uniform NL=10.
//  - Each block stores 19w' x 9k x 512c = 350 KB fully CONTIGUOUS
//    (vs R7's 2KB scatter chunks at 18KB stride) -> fill-kernel-class streams.
//  - Thread = channel. Loads 3 clamped rows x 10 float2 into v[3][20]
//    (~90 VGPR, no spill, 2 x 8-wave blocks/CU).
//  - XCD pin: xcd = blockIdx&7 owns b in {xcd, xcd+8}; per-b input 2.95 MB
//    < 4 MB XCD L2 -> h-row 3x reuse + half-overlap served by L2.
//  - nt stores (no-RFO verified R6).
// Predicted: FETCH ~90->~55 MB, WRITE 426 MB unchanged, kernel ~110->85-97us,
// dur_us 451.5 -> ~428-438.

#define BB 16
#define CC 512
#define HH 38
#define WW 38
#define HW (HH * WW)      // 1444
#define KK 9
#define NT 512

// Halves: HALF=0 covers w' 0..18 (window floats 0..19,  WA=0,  NL=10)
//         HALF=1 covers w' 19..37 (window floats 18..37, WA=18, NL=10)
template <int HALF>
__device__ __forceinline__ void do_half(const float* __restrict__ fm,
                                        float* __restrict__ out,
                                        int b, int hp, int c)
{
    constexpr int W0 = HALF * 19;
    constexpr int WN = 19;
    constexpr int WA = HALF * 18;
    constexpr int NL = 10;          // float2 loads per row, window = 20 floats

    const int r0 = (hp > 0) ? hp - 1 : 0;
    const int r2 = (hp < HH - 1) ? hp + 1 : HH - 1;
    const int rows[3] = { r0, hp, r2 };

    const float* plane = fm + (size_t)(b * CC + c) * HW;

    // ---- load 3 clamped rows' float2 windows (static v indices) ----
    float v[3][2 * NL];
    #pragma unroll
    for (int di = 0; di < 3; ++di) {
        const float2* src = (const float2*)(plane + rows[di] * WW + WA);
        #pragma unroll
        for (int i = 0; i < NL; ++i) {
            const float2 t = src[i];
            v[di][2 * i + 0] = t.x;
            v[di][2 * i + 1] = t.y;
        }
    }

    // ---- contiguous store stream: w' major, k = di*3+dj minor ----
    // Per (w',k): 512c x 4B = 2KB chunk, consecutive chunks -> 350 KB
    // sequential per block. Lanes c-consecutive -> full-line segments.
    float* outp = out + (size_t)((b * HW + hp * WW + W0) * KK) * CC + c;
    #pragma unroll
    for (int wi = 0; wi < WN; ++wi) {
        #pragma unroll
        for (int di = 0; di < 3; ++di) {
            #pragma unroll
            for (int dj = 0; dj < 3; ++dj) {
                int wj = W0 + wi + dj - 1;             // compile-time under unroll
                wj = wj < 0 ? 0 : (wj > WW - 1 ? WW - 1 : wj);
                __builtin_nontemporal_store(
                    v[di][wj - WA],
                    outp + (size_t)(wi * KK + di * 3 + dj) * CC);
            }
        }
    }
}

__global__ __launch_bounds__(NT) void spatial_pool_gather(
    const float* __restrict__ fm, float* __restrict__ out)
{
    // XCD-pinning swizzle (dispatch round-robins blockIdx over 8 XCDs):
    //   xcd = L & 7 owns b in {xcd, xcd+8}; b-major then h'-major so the
    //   2.95 MB per-b input stays resident in that XCD's 4 MB L2.
    const unsigned L = blockIdx.x;          // 0..1215
    const int xcd  = (int)(L & 7u);
    const int slot = (int)(L >> 3);         // 0..151
    const int bsel = slot / 76;             // 0..1
    const int rem  = slot - bsel * 76;      // 0..75
    const int hp   = rem >> 1;              // 0..37
    const int half = rem & 1;               // 0..1
    const int b    = xcd + 8 * bsel;        // 0..15
    const int c    = (int)threadIdx.x;      // 0..511

    if (half == 0) do_half<0>(fm, out, b, hp, c);
    else           do_half<1>(fm, out, b, hp, c);
}

extern "C" void kernel_launch(void* const* d_in, const int* in_sizes, int n_in,
                              void* d_out, int out_size, void* d_ws, size_t ws_size,
                              hipStream_t stream) {
    const float* fm = (const float*)d_in[0];
    float* out = (float*)d_out;
    dim3 grid(BB * HH * 2);   // 1216 blocks = 8 XCDs x 152
    dim3 block(NT);
    spatial_pool_gather<<<grid, block, 0, stream>>>(fm, out);
}

// Round 4
// 454.378 us; speedup vs baseline: 1.0195x; 1.0195x over previous
//
#include <hip/hip_runtime.h>

// SpatialPool: fm [B=16, C=512, H=38, W=38] f32, replication pad 1,
// out[b, (h*W+w)*9*C + k*C + c] = fm[b, c, clamp(h+k/3-1), clamp(w+k%3-1)]
//
// R9: STORE WIDTH experiment. R7 (scatter, 2KB chunks) ~110us and R8c
// (gather, 350KB contiguous streams, XCD-pinned reads, balanced grid) ~116us
// are EQUAL within noise -> bytes & store placement exonerated. Both used
// 4B/lane dword stores (256B/wave). The proven 6.29 TB/s pattern (m13) is a
// float4 copy: 16B/lane, 1KB/wave. fillBufferAligned (6.2 TB/s on this
// trace) also stores x4. hipcc never widens accesses (G13).
//  - Thread owns 4 consecutive channels c0=4*cg -> each (w',k) store is ONE
//    f32x4 nt store; wave = 1KB contiguous. 106M dword stores -> 26.6M x4.
//  - Block = (b, h', quadrant): 16*38*4 = 2432 blocks x 256 thr (9.5/CU,
//    1.05 imbalance). cg = tid&127, sub = tid>>7 (WAVE-UNIFORM switch ->
//    no divergence); 8 static (W0,WN,WA) cases -> all reg indices static.
//  - Loads float2 (row stride 38 floats blocks float4 alignment on odd rows).
//  - XCD pin, nt stores, contiguous block span: unchanged from R8c.
// Predicted: VGPR ~130, kernel 116 -> ~85-95us, dur 463 -> ~432-442 if store
// width is the limiter; neutral -> next single-toggle A/B is nt->plain.

#define BB 16
#define CC 512
#define HH 38
#define WW 38
#define HW (HH * WW)      // 1444
#define KK 9
#define NT 256

typedef float f32x2 __attribute__((ext_vector_type(2)));
typedef float f32x4 __attribute__((ext_vector_type(4)));

// 8 w-sub-ranges: ws -> covers w' in [W0, W0+WN); loads floats [WA, WA+2*NL)
// of each clamped row (always in-bounds, always covering clamp(W0-1..W0+WN)).
//   ws: 0:(0,5,0,3) 1:(5,5,4,4) 2:(10,5,8,4) 3:(15,4,14,3)
//       4:(19,5,18,4) 5:(24,5,22,4) 6:(29,5,28,4) 7:(34,4,32,3)
template <int W0, int WN, int WA, int NL>
__device__ __forceinline__ void do_sub(const float* __restrict__ fm,
                                       float* __restrict__ out,
                                       int b, int hp, int c0)
{
    const int r0 = (hp > 0) ? hp - 1 : 0;
    const int r2 = (hp < HH - 1) ? hp + 1 : HH - 1;
    const int rows[3] = { r0, hp, r2 };

    const float* p0 = fm + (size_t)(b * CC + c0 + 0) * HW;
    const float* p1 = fm + (size_t)(b * CC + c0 + 1) * HW;
    const float* p2 = fm + (size_t)(b * CC + c0 + 2) * HW;
    const float* p3 = fm + (size_t)(b * CC + c0 + 3) * HW;

    // vv[di][j] = input float (WA+j) of row di, packed across channels
    // c0..c0+3 in .x/.y/.z/.w -> ready-made f32x4 store operand.
    f32x4 vv[3][2 * NL];
    #pragma unroll
    for (int di = 0; di < 3; ++di) {
        const int ro = rows[di] * WW + WA;
        #pragma unroll
        for (int i = 0; i < NL; ++i) {
            const f32x2 t0 = *(const f32x2*)(p0 + ro + 2 * i);
            const f32x2 t1 = *(const f32x2*)(p1 + ro + 2 * i);
            const f32x2 t2 = *(const f32x2*)(p2 + ro + 2 * i);
            const f32x2 t3 = *(const f32x2*)(p3 + ro + 2 * i);
            vv[di][2 * i + 0] = (f32x4){t0.x, t1.x, t2.x, t3.x};
            vv[di][2 * i + 1] = (f32x4){t0.y, t1.y, t2.y, t3.y};
        }
    }

    // ---- stores: 16B/lane, wave = 1KB contiguous; block span contiguous ----
    float* outp = out + (size_t)((b * HW + hp * WW + W0) * KK) * CC + c0;
    #pragma unroll
    for (int wi = 0; wi < WN; ++wi) {
        #pragma unroll
        for (int di = 0; di < 3; ++di) {
            #pragma unroll
            for (int dj = 0; dj < 3; ++dj) {
                int wj = W0 + wi + dj - 1;             // compile-time under unroll
                wj = wj < 0 ? 0 : (wj > WW - 1 ? WW - 1 : wj);
                __builtin_nontemporal_store(
                    vv[di][wj - WA],
                    (f32x4*)(outp + (size_t)(wi * KK + di * 3 + dj) * CC));
            }
        }
    }
}

__global__ __launch_bounds__(NT) void spatial_pool_x4(
    const float* __restrict__ fm, float* __restrict__ out)
{
    // XCD pin: xcd = L&7 owns b in {xcd, xcd+8} (per-b input 2.95MB < 4MB L2)
    const unsigned L = blockIdx.x;          // 0..2431
    const int xcd  = (int)(L & 7u);
    const int slot = (int)(L >> 3);         // 0..303
    const int bsel = slot / 152;            // 0..1
    const int rem  = slot - bsel * 152;     // 0..151
    const int hp   = rem >> 2;              // 0..37
    const int qq   = rem & 3;               // 0..3
    const int b    = xcd + 8 * bsel;        // 0..15

    const int tid = (int)threadIdx.x;       // 0..255
    const int cg  = tid & 127;              // channel group
    const int sub = tid >> 7;               // 0..1, wave-uniform
    const int c0  = 4 * cg;
    const int ws  = qq * 2 + sub;           // 0..7, wave-uniform

    switch (ws) {
        case 0:  do_sub< 0, 5,  0, 3>(fm, out, b, hp, c0); break;
        case 1:  do_sub< 5, 5,  4, 4>(fm, out, b, hp, c0); break;
        case 2:  do_sub<10, 5,  8, 4>(fm, out, b, hp, c0); break;
        case 3:  do_sub<15, 4, 14, 3>(fm, out, b, hp, c0); break;
        case 4:  do_sub<19, 5, 18, 4>(fm, out, b, hp, c0); break;
        case 5:  do_sub<24, 5, 22, 4>(fm, out, b, hp, c0); break;
        case 6:  do_sub<29, 5, 28, 4>(fm, out, b, hp, c0); break;
        default: do_sub<34, 4, 32, 3>(fm, out, b, hp, c0); break;
    }
}

extern "C" void kernel_launch(void* const* d_in, const int* in_sizes, int n_in,
                              void* d_out, int out_size, void* d_ws, size_t ws_size,
                              hipStream_t stream) {
    const float* fm = (const float*)d_in[0];
    float* out = (float*)d_out;
    dim3 grid(BB * HH * 4);   // 2432 blocks = 8 XCDs x 304
    dim3 block(NT);
    spatial_pool_x4<<<grid, block, 0, stream>>>(fm, out);
}